// Round 1
// baseline (678.306 us; speedup 1.0000x reference)
//
#include <hip/hip_runtime.h>
#include <math.h>

#define ALIGN16 __attribute__((aligned(16)))

__device__ __forceinline__ float tanh_fast(float x) {
  float ax = fabsf(x);
  float t  = __expf(-2.0f * ax);
  float r  = (1.0f - t) * __builtin_amdgcn_rcpf(1.0f + t);
  return copysignf(r, x);
}

// One block per batch element. 256 threads (4 waves), 1 block/CU.
// Encoder: thread roles re-mapped per phase:
//   hs-GEMM: (u=lane, p=wave) partials; attention: f=tid; z-GEMM: k=tid.
// enc_kernel column cached in 256 VGPRs/thread; enc_rec in LDS (sW).
__global__ __launch_bounds__(256, 1)
void darnn_fused(const float* __restrict__ gin,   // [256][64][256]
                 const float* __restrict__ eKg,   // [256][256]
                 const float* __restrict__ eRg,   // [64][256]
                 const float* __restrict__ ebg,   // [256]
                 const float* __restrict__ dKg,   // [64][256]
                 const float* __restrict__ dRg,   // [64][256]
                 const float* __restrict__ dbg,   // [256]
                 const float* __restrict__ aeW,   // [192][64]
                 const float* __restrict__ aeb,   // [64]
                 const float* __restrict__ aev,   // [64]
                 const float* __restrict__ adW,   // [192][64]
                 const float* __restrict__ adb,   // [64]
                 const float* __restrict__ adv,   // [64]
                 const float* __restrict__ fcW,   // [65][64]
                 const float* __restrict__ fcb,   // [64]
                 const float* __restrict__ fcfW,  // [128][256]
                 const float* __restrict__ fcfb,  // [256]
                 float* __restrict__ out)         // [256][256]
{
  __shared__ ALIGN16 float sW[16384];       // We_x staging -> enc_rec -> Wd_x
  __shared__ ALIGN16 float s_xenc[64 * 65]; // x_encoded, padded stride 65
  __shared__ ALIGN16 float s_xtld[256];
  __shared__ ALIGN16 float s_ag[256];
  __shared__ ALIGN16 float s_red[256];
  __shared__ ALIGN16 float s_redB[256];
  __shared__ ALIGN16 float s_hs[64];
  __shared__ ALIGN16 float s_h[64];
  __shared__ ALIGN16 float s_c[64];
  __shared__ ALIGN16 float s_aev[64];
  __shared__ ALIGN16 float s_adv[64];
  __shared__ ALIGN16 float s_beta[64];
  __shared__ ALIGN16 float s_ctx[64];
  __shared__ ALIGN16 float s_yt[64];
  __shared__ ALIGN16 float s_yprev[64];

  const int tid  = threadIdx.x;
  const int lane = tid & 63;
  const int wv   = tid >> 6;
  const int b    = blockIdx.x;
  const float* inb = gin + (size_t)b * (64 * 256);

  // ---------------- prologue: stage We_x (aeW rows 128..191), init ----------------
  for (int i = tid; i < 4096; i += 256) sW[i] = aeW[128 * 64 + i];
  if (tid < 64) { s_aev[tid] = aev[tid]; s_h[tid] = 0.f; s_c[tid] = 0.f; }
  __syncthreads();

  // x_proj[f=tid][u] = sum_t in[b][t][f] * We_x[t][u]   (kept in 64 VGPRs)
  float xp[64];
#pragma unroll
  for (int u = 0; u < 64; ++u) xp[u] = 0.f;
  for (int t0 = 0; t0 < 64; t0 += 8) {
    float xv[8];
#pragma unroll
    for (int q = 0; q < 8; ++q) xv[q] = inb[(t0 + q) * 256 + tid];
#pragma unroll
    for (int q = 0; q < 8; ++q) {
#pragma unroll
      for (int u4 = 0; u4 < 16; ++u4) {
        float4 w = *(const float4*)&sW[(t0 + q) * 64 + u4 * 4];
        xp[u4 * 4 + 0] = fmaf(xv[q], w.x, xp[u4 * 4 + 0]);
        xp[u4 * 4 + 1] = fmaf(xv[q], w.y, xp[u4 * 4 + 1]);
        xp[u4 * 4 + 2] = fmaf(xv[q], w.z, xp[u4 * 4 + 2]);
        xp[u4 * 4 + 3] = fmaf(xv[q], w.w, xp[u4 * 4 + 3]);
      }
    }
  }
  __syncthreads();  // done with We_x in sW

  // enc_rec -> LDS ; enc_kernel column -> VGPRs
  for (int i = tid; i < 16384; i += 256) sW[i] = eRg[i];
  float eKr[256];
#pragma unroll
  for (int f = 0; f < 256; ++f) eKr[f] = eKg[f * 256 + tid];
  float wh[16], wsr[16];
#pragma unroll
  for (int jj = 0; jj < 16; ++jj) {
    wh[jj]  = aeW[(wv * 16 + jj) * 64 + lane];        // We_h[j][u]
    wsr[jj] = aeW[(64 + wv * 16 + jj) * 64 + lane];   // We_s[j][u]
  }
  const float aeb_u = aeb[lane];
  const float eb_k  = ebg[tid];
  __syncthreads();

  // ---------------- encoder loop ----------------
  for (int t = 0; t < 64; ++t) {
    float xtv = inb[t * 256 + tid];  // prefetch x_t[f=tid]
    // A: hs partials (u=lane, p=wv)
    float p0 = 0.f, p1 = 0.f;
#pragma unroll
    for (int jj = 0; jj < 16; ++jj) {
      int j = wv * 16 + jj;
      p0 = fmaf(s_h[j], wh[jj], p0);
      p1 = fmaf(s_c[j], wsr[jj], p1);
    }
    s_red[tid] = p0 + p1;
    __syncthreads();
    // B: hs final
    if (wv == 0)
      s_hs[lane] = s_red[lane] + s_red[64 + lane] + s_red[128 + lane] + s_red[192 + lane] + aeb_u;
    __syncthreads();
    // C: scores (f=tid), block softmax over 256
    float sc0 = 0.f, sc1 = 0.f, sc2 = 0.f, sc3 = 0.f;
#pragma unroll
    for (int u4 = 0; u4 < 16; ++u4) {
      float4 hv = *(const float4*)&s_hs[u4 * 4];
      float4 vv = *(const float4*)&s_aev[u4 * 4];
      sc0 = fmaf(tanh_fast(hv.x + xp[u4 * 4 + 0]), vv.x, sc0);
      sc1 = fmaf(tanh_fast(hv.y + xp[u4 * 4 + 1]), vv.y, sc1);
      sc2 = fmaf(tanh_fast(hv.z + xp[u4 * 4 + 2]), vv.z, sc2);
      sc3 = fmaf(tanh_fast(hv.w + xp[u4 * 4 + 3]), vv.w, sc3);
    }
    float sc = (sc0 + sc1) + (sc2 + sc3);
    float m = sc;
#pragma unroll
    for (int d = 1; d < 64; d <<= 1) m = fmaxf(m, __shfl_xor(m, d));
    if (lane == 0) s_redB[wv] = m;
    __syncthreads();
    {
      float4 mm = *(const float4*)&s_redB[0];
      m = fmaxf(fmaxf(mm.x, mm.y), fmaxf(mm.z, mm.w));
    }
    float pe = __expf(sc - m);
    float ssum = pe;
#pragma unroll
    for (int d = 1; d < 64; d <<= 1) ssum += __shfl_xor(ssum, d);
    if (lane == 0) s_redB[8 + wv] = ssum;
    __syncthreads();
    float S;
    {
      float4 sv = *(const float4*)&s_redB[8];
      S = (sv.x + sv.y) + (sv.z + sv.w);
    }
    s_xtld[tid] = (pe / S) * xtv;
    __syncthreads();
    // D: z-GEMM (k=tid): x_tilde @ eK + h @ eR + eb
    float a0 = eb_k, a1 = 0.f, a2 = 0.f, a3 = 0.f;
#pragma unroll
    for (int f4 = 0; f4 < 64; ++f4) {
      float4 xt = *(const float4*)&s_xtld[f4 * 4];
      a0 = fmaf(xt.x, eKr[f4 * 4 + 0], a0);
      a1 = fmaf(xt.y, eKr[f4 * 4 + 1], a1);
      a2 = fmaf(xt.z, eKr[f4 * 4 + 2], a2);
      a3 = fmaf(xt.w, eKr[f4 * 4 + 3], a3);
    }
#pragma unroll
    for (int j4 = 0; j4 < 16; ++j4) {
      float4 hv = *(const float4*)&s_h[j4 * 4];
      a0 = fmaf(hv.x, sW[(j4 * 4 + 0) * 256 + tid], a0);
      a1 = fmaf(hv.y, sW[(j4 * 4 + 1) * 256 + tid], a1);
      a2 = fmaf(hv.z, sW[(j4 * 4 + 2) * 256 + tid], a2);
      a3 = fmaf(hv.w, sW[(j4 * 4 + 3) * 256 + tid], a3);
    }
    float acc = (a0 + a1) + (a2 + a3);
    float a = (wv == 2) ? tanhf(acc) : (1.0f / (1.0f + expf(-acc)));
    s_ag[tid] = a;
    __syncthreads();
    if (tid < 64) {
      float cn = s_ag[64 + tid] * s_c[tid] + s_ag[tid] * s_ag[128 + tid];
      float hn = s_ag[192 + tid] * tanhf(cn);
      s_c[tid] = cn;
      s_h[tid] = hn;
      s_xenc[t * 65 + tid] = hn;
    }
    __syncthreads();
  }

  // ---------------- decoder prologue ----------------
  for (int i = tid; i < 4096; i += 256) sW[i] = adW[128 * 64 + i];  // Wd_x
  if (tid < 64) {
    s_adv[tid]   = adv[tid];
    s_yprev[tid] = inb[tid * 256 + 255];
    s_h[tid] = 0.f; s_c[tid] = 0.f;
  }
  float dKr[64], dRr[64];
#pragma unroll
  for (int j = 0; j < 64; ++j) { dKr[j] = dKg[j * 256 + tid]; dRr[j] = dRg[j * 256 + tid]; }
  float wdd[16], wdc[16], fcwr[16];
#pragma unroll
  for (int jj = 0; jj < 16; ++jj) {
    wdd[jj]  = adW[(wv * 16 + jj) * 64 + lane];       // Wd_d[j][u]
    wdc[jj]  = adW[(64 + wv * 16 + jj) * 64 + lane];  // Wd_c[j][u]
    fcwr[jj] = fcW[(wv * 16 + jj) * 64 + lane];       // fc_W[i][j]
  }
  const float adb_u = adb[lane];
  const float db_k  = dbg[tid];
  const float fcb_j = fcb[lane];
  const float fcw65 = fcW[64 * 64 + lane];
  __syncthreads();
  // xe_proj (t=lane, u = wv*16+ui), kept in 16 VGPRs
  float xep[16];
#pragma unroll
  for (int ui = 0; ui < 16; ++ui) xep[ui] = 0.f;
  for (int e = 0; e < 64; ++e) {
    float xv = s_xenc[lane * 65 + e];
#pragma unroll
    for (int u4 = 0; u4 < 4; ++u4) {
      float4 w = *(const float4*)&sW[e * 64 + wv * 16 + u4 * 4];
      xep[u4 * 4 + 0] = fmaf(xv, w.x, xep[u4 * 4 + 0]);
      xep[u4 * 4 + 1] = fmaf(xv, w.y, xep[u4 * 4 + 1]);
      xep[u4 * 4 + 2] = fmaf(xv, w.z, xep[u4 * 4 + 2]);
      xep[u4 * 4 + 3] = fmaf(xv, w.w, xep[u4 * 4 + 3]);
    }
  }

  // ---------------- decoder loop ----------------
  for (int t = 0; t < 64; ++t) {
    // A: dc partials
    float p0 = 0.f, p1 = 0.f;
#pragma unroll
    for (int jj = 0; jj < 16; ++jj) {
      int j = wv * 16 + jj;
      p0 = fmaf(s_h[j], wdd[jj], p0);
      p1 = fmaf(s_c[j], wdc[jj], p1);
    }
    s_red[tid] = p0 + p1;
    __syncthreads();
    if (wv == 0)
      s_hs[lane] = s_red[lane] + s_red[64 + lane] + s_red[128 + lane] + s_red[192 + lane] + adb_u;
    __syncthreads();
    // C: scores (tt=lane, u-slice per wave)
    float ps0 = 0.f, ps1 = 0.f;
#pragma unroll
    for (int u4 = 0; u4 < 4; ++u4) {
      float4 dcv = *(const float4*)&s_hs[wv * 16 + u4 * 4];
      float4 vv  = *(const float4*)&s_adv[wv * 16 + u4 * 4];
      ps0 = fmaf(tanh_fast(dcv.x + xep[u4 * 4 + 0]), vv.x, ps0);
      ps1 = fmaf(tanh_fast(dcv.y + xep[u4 * 4 + 1]), vv.y, ps1);
      ps0 = fmaf(tanh_fast(dcv.z + xep[u4 * 4 + 2]), vv.z, ps0);
      ps1 = fmaf(tanh_fast(dcv.w + xep[u4 * 4 + 3]), vv.w, ps1);
    }
    s_redB[tid] = ps0 + ps1;
    __syncthreads();
    float sct = s_redB[lane] + s_redB[64 + lane] + s_redB[128 + lane] + s_redB[192 + lane];
    // in-wave softmax over 64 (all waves redundantly)
    float m = sct;
#pragma unroll
    for (int d = 1; d < 64; d <<= 1) m = fmaxf(m, __shfl_xor(m, d));
    float pe = __expf(sct - m);
    float ssum = pe;
#pragma unroll
    for (int d = 1; d < 64; d <<= 1) ssum += __shfl_xor(ssum, d);
    float beta = pe / ssum;
    if (wv == 0) s_beta[lane] = beta;
    __syncthreads();
    // E: context partial (e=lane, t-slice per wave)
    float pc = 0.f;
#pragma unroll
    for (int t4 = 0; t4 < 4; ++t4) {
      float4 bv = *(const float4*)&s_beta[wv * 16 + t4 * 4];
      pc = fmaf(bv.x, s_xenc[(wv * 16 + t4 * 4 + 0) * 65 + lane], pc);
      pc = fmaf(bv.y, s_xenc[(wv * 16 + t4 * 4 + 1) * 65 + lane], pc);
      pc = fmaf(bv.z, s_xenc[(wv * 16 + t4 * 4 + 2) * 65 + lane], pc);
      pc = fmaf(bv.w, s_xenc[(wv * 16 + t4 * 4 + 3) * 65 + lane], pc);
    }
    s_red[tid] = pc;
    __syncthreads();
    if (wv == 0)
      s_ctx[lane] = s_red[lane] + s_red[64 + lane] + s_red[128 + lane] + s_red[192 + lane];
    __syncthreads();
    // G: y_tilde partial (j=lane, i-slice per wave)
    float py = 0.f;
#pragma unroll
    for (int i4 = 0; i4 < 4; ++i4) {
      float4 cv = *(const float4*)&s_ctx[wv * 16 + i4 * 4];
      py = fmaf(cv.x, fcwr[i4 * 4 + 0], py);
      py = fmaf(cv.y, fcwr[i4 * 4 + 1], py);
      py = fmaf(cv.z, fcwr[i4 * 4 + 2], py);
      py = fmaf(cv.w, fcwr[i4 * 4 + 3], py);
    }
    s_redB[tid] = py;
    __syncthreads();
    float y_t = s_yprev[t];
    if (wv == 0)
      s_yt[lane] = s_redB[lane] + s_redB[64 + lane] + s_redB[128 + lane] + s_redB[192 + lane]
                   + fcb_j + y_t * fcw65;
    __syncthreads();
    // I: z (k=tid): y_tilde @ dK + d @ dR + db
    float a0 = db_k, a1 = 0.f, a2 = 0.f, a3 = 0.f;
#pragma unroll
    for (int j4 = 0; j4 < 16; ++j4) {
      float4 yv = *(const float4*)&s_yt[j4 * 4];
      a0 = fmaf(yv.x, dKr[j4 * 4 + 0], a0);
      a1 = fmaf(yv.y, dKr[j4 * 4 + 1], a1);
      a2 = fmaf(yv.z, dKr[j4 * 4 + 2], a2);
      a3 = fmaf(yv.w, dKr[j4 * 4 + 3], a3);
      float4 dv = *(const float4*)&s_h[j4 * 4];
      a0 = fmaf(dv.x, dRr[j4 * 4 + 0], a0);
      a1 = fmaf(dv.y, dRr[j4 * 4 + 1], a1);
      a2 = fmaf(dv.z, dRr[j4 * 4 + 2], a2);
      a3 = fmaf(dv.w, dRr[j4 * 4 + 3], a3);
    }
    float acc = (a0 + a1) + (a2 + a3);
    float a = (wv == 2) ? tanhf(acc) : (1.0f / (1.0f + expf(-acc)));
    s_ag[tid] = a;
    __syncthreads();
    if (tid < 64) {
      float cn = s_ag[64 + tid] * s_c[tid] + s_ag[tid] * s_ag[128 + tid];
      float hn = s_ag[192 + tid] * tanhf(cn);
      s_c[tid] = cn;
      s_h[tid] = hn;
    }
    __syncthreads();
  }

  // ---------------- epilogue: y = [d_n, ctx] @ fcfW + fcfb ----------------
  float a0 = fcfb[tid], a1 = 0.f, a2 = 0.f, a3 = 0.f;
#pragma unroll
  for (int j4 = 0; j4 < 16; ++j4) {
    float4 dv = *(const float4*)&s_h[j4 * 4];
    a0 = fmaf(dv.x, fcfW[(j4 * 4 + 0) * 256 + tid], a0);
    a1 = fmaf(dv.y, fcfW[(j4 * 4 + 1) * 256 + tid], a1);
    a2 = fmaf(dv.z, fcfW[(j4 * 4 + 2) * 256 + tid], a2);
    a3 = fmaf(dv.w, fcfW[(j4 * 4 + 3) * 256 + tid], a3);
    float4 cv = *(const float4*)&s_ctx[j4 * 4];
    a0 = fmaf(cv.x, fcfW[(64 + j4 * 4 + 0) * 256 + tid], a0);
    a1 = fmaf(cv.y, fcfW[(64 + j4 * 4 + 1) * 256 + tid], a1);
    a2 = fmaf(cv.z, fcfW[(64 + j4 * 4 + 2) * 256 + tid], a2);
    a3 = fmaf(cv.w, fcfW[(64 + j4 * 4 + 3) * 256 + tid], a3);
  }
  out[b * 256 + tid] = (a0 + a1) + (a2 + a3);
}

extern "C" void kernel_launch(void* const* d_in, const int* in_sizes, int n_in,
                              void* d_out, int out_size, void* d_ws, size_t ws_size,
                              hipStream_t stream) {
  const float* gin  = (const float*)d_in[0];
  const float* eK   = (const float*)d_in[1];
  const float* eR   = (const float*)d_in[2];
  const float* eb   = (const float*)d_in[3];
  const float* dK   = (const float*)d_in[4];
  const float* dR   = (const float*)d_in[5];
  const float* db   = (const float*)d_in[6];
  const float* aeW  = (const float*)d_in[7];
  const float* aeb  = (const float*)d_in[8];
  const float* aev  = (const float*)d_in[9];
  // d_in[10] = attn_e_vb: constant shift, cancels in softmax
  const float* adW  = (const float*)d_in[11];
  const float* adb  = (const float*)d_in[12];
  const float* adv  = (const float*)d_in[13];
  // d_in[14] = attn_d_vb: cancels in softmax
  const float* fcW  = (const float*)d_in[15];
  const float* fcb  = (const float*)d_in[16];
  const float* fcfW = (const float*)d_in[17];
  const float* fcfb = (const float*)d_in[18];
  float* out = (float*)d_out;

  const int B = in_sizes[0] / (64 * 256);
  hipLaunchKernelGGL(darnn_fused, dim3(B), dim3(256), 0, stream,
                     gin, eK, eR, eb, dK, dR, db, aeW, aeb, aev,
                     adW, adb, adv, fcW, fcb, fcfW, fcfb, out);
}

// Round 2
// 444.651 us; speedup vs baseline: 1.5255x; 1.5255x over previous
//
#include <hip/hip_runtime.h>
#include <math.h>

#define ALIGN16 __attribute__((aligned(16)))

__device__ __forceinline__ float rcpf_(float x){ return __builtin_amdgcn_rcpf(x); }
__device__ __forceinline__ float tanh_e(float x){
  float t = __expf(2.0f*x);
  return (t - 1.0f) * rcpf_(t + 1.0f);
}
__device__ __forceinline__ float sigm(float x){
  return rcpf_(1.0f + __expf(-x));
}

// One block (512 threads, 8 waves) per batch element; 256 blocks = 1/CU.
// Pair decomposition: f = tid>>1 (output index), half = tid&1 (reduction slice)
// -> cross-half combine is a single shfl_xor(.,1). 8-thread groups (u8,grp)
// for the 64-wide attention pre-activations.
__global__ __launch_bounds__(512)
void darnn_fused(const float* __restrict__ gin,   // [256][64][256]
                 const float* __restrict__ eKg,   // [256][256]
                 const float* __restrict__ eRg,   // [64][256]
                 const float* __restrict__ ebg,   // [256]
                 const float* __restrict__ dKg,   // [64][256]
                 const float* __restrict__ dRg,   // [64][256]
                 const float* __restrict__ dbg,   // [256]
                 const float* __restrict__ aeW,   // [192][64]
                 const float* __restrict__ aeb,   // [64]
                 const float* __restrict__ aev,   // [64]
                 const float* __restrict__ adW,   // [192][64]
                 const float* __restrict__ adb,   // [64]
                 const float* __restrict__ adv,   // [64]
                 const float* __restrict__ fcW,   // [65][64]
                 const float* __restrict__ fcb,   // [64]
                 const float* __restrict__ fcfW,  // [128][256]
                 const float* __restrict__ fcfb,  // [256]
                 float* __restrict__ out)         // [256][256]
{
  __shared__ ALIGN16 float sW[8256];        // We_x (enc) -> Wd_x + fcW (dec)
  __shared__ ALIGN16 float sWT[256*68];     // enc_rec^T [k][j], stride 68
  __shared__ ALIGN16 float s_xenc[64*65];
  __shared__ ALIGN16 float s_xtld[256];
  __shared__ ALIGN16 float s_ag[256];
  __shared__ ALIGN16 float s_hs[64];        // E_u = exp(2*preact_u)
  __shared__ ALIGN16 float s_h[64];
  __shared__ ALIGN16 float s_c[64];
  __shared__ ALIGN16 float s_aev[64];
  __shared__ ALIGN16 float s_pe[64];
  __shared__ ALIGN16 float s_ctx[64];
  __shared__ ALIGN16 float s_yprev[64];
  __shared__ ALIGN16 float s_redB[64];

  const int tid  = threadIdx.x;
  const int lane = tid & 63;
  const int wv   = tid >> 6;   // 0..7
  const int f    = tid >> 1;   // 0..255
  const int half = tid & 1;
  const int u8   = tid >> 3;   // 0..63
  const int grp  = tid & 7;
  const int b    = blockIdx.x;
  const float* inb = gin + (size_t)b * (64*256);

  // ---------------- encoder prologue ----------------
  for (int i = tid; i < 4096; i += 512) sW[i] = aeW[128*64 + i];   // We_x
  if (tid < 64) { s_aev[tid] = aev[tid]; s_h[tid] = 0.f; s_c[tid] = 0.f; }
  __syncthreads();

  // x_proj[f][u'] for u' in half*32+[0,32), then P = exp(2*xp)  (step-invariant)
  float P[32];
#pragma unroll
  for (int i = 0; i < 32; ++i) P[i] = 0.f;
  for (int t = 0; t < 64; ++t) {
    float xv = inb[t*256 + f];
#pragma unroll
    for (int q4 = 0; q4 < 8; ++q4) {
      float4 w = *(const float4*)&sW[t*64 + half*32 + q4*4];
      P[q4*4+0] = fmaf(xv, w.x, P[q4*4+0]);
      P[q4*4+1] = fmaf(xv, w.y, P[q4*4+1]);
      P[q4*4+2] = fmaf(xv, w.z, P[q4*4+2]);
      P[q4*4+3] = fmaf(xv, w.w, P[q4*4+3]);
    }
  }
#pragma unroll
  for (int i = 0; i < 32; ++i) P[i] = __expf(2.0f*P[i]);

  // enc_rec transposed into LDS: sWT[k*68 + j] = eR[j][k]
  for (int i = tid; i < 16384; i += 512) sWT[(i & 255)*68 + (i >> 8)] = eRg[i];

  float eKr[128];
#pragma unroll
  for (int q = 0; q < 128; ++q) eKr[q] = eKg[(half*128 + q)*256 + f];
  float wh[8], wsr[8];
#pragma unroll
  for (int jj = 0; jj < 8; ++jj) {
    wh[jj]  = aeW[(grp*8+jj)*64 + u8];        // We_h[j][u8]
    wsr[jj] = aeW[(64+grp*8+jj)*64 + u8];     // We_s[j][u8]
  }
  const float aeb_u = aeb[u8];
  const float eb_k  = ebg[f];
  __syncthreads();

  // ---------------- encoder loop ----------------
  for (int t = 0; t < 64; ++t) {
    float xtv = inb[t*256 + f];
    // A: hs_u via 8-thread groups, combine by shfl; E_u = exp(2*hs_u)
    float4 h0 = *(const float4*)&s_h[grp*8];
    float4 h1 = *(const float4*)&s_h[grp*8+4];
    float4 c0 = *(const float4*)&s_c[grp*8];
    float4 c1 = *(const float4*)&s_c[grp*8+4];
    float p = 0.f;
    p = fmaf(h0.x, wh[0], p);  p = fmaf(h0.y, wh[1], p);
    p = fmaf(h0.z, wh[2], p);  p = fmaf(h0.w, wh[3], p);
    p = fmaf(h1.x, wh[4], p);  p = fmaf(h1.y, wh[5], p);
    p = fmaf(h1.z, wh[6], p);  p = fmaf(h1.w, wh[7], p);
    p = fmaf(c0.x, wsr[0], p); p = fmaf(c0.y, wsr[1], p);
    p = fmaf(c0.z, wsr[2], p); p = fmaf(c0.w, wsr[3], p);
    p = fmaf(c1.x, wsr[4], p); p = fmaf(c1.y, wsr[5], p);
    p = fmaf(c1.z, wsr[6], p); p = fmaf(c1.w, wsr[7], p);
    p += __shfl_xor(p, 1); p += __shfl_xor(p, 2); p += __shfl_xor(p, 4);
    float E = __expf(2.0f*(p + aeb_u));
    if (grp == 0) s_hs[u8] = E;
    __syncthreads();                                   // b1

    // C: scores via tanh = (E*P-1)/(E*P+1); softmax w/o max-sub; unnorm x_tilde
    float sc = 0.f;
#pragma unroll
    for (int q4 = 0; q4 < 8; ++q4) {
      float4 Ev = *(const float4*)&s_hs[half*32 + q4*4];
      float4 vv = *(const float4*)&s_aev[half*32 + q4*4];
      float q0 = Ev.x*P[q4*4+0], q1 = Ev.y*P[q4*4+1];
      float q2 = Ev.z*P[q4*4+2], q3 = Ev.w*P[q4*4+3];
      sc = fmaf((q0-1.f)*rcpf_(q0+1.f), vv.x, sc);
      sc = fmaf((q1-1.f)*rcpf_(q1+1.f), vv.y, sc);
      sc = fmaf((q2-1.f)*rcpf_(q2+1.f), vv.z, sc);
      sc = fmaf((q3-1.f)*rcpf_(q3+1.f), vv.w, sc);
    }
    sc += __shfl_xor(sc, 1);
    float pe = __expf(sc);
    float ws = pe;
    ws += __shfl_xor(ws, 1);  ws += __shfl_xor(ws, 2);
    ws += __shfl_xor(ws, 4);  ws += __shfl_xor(ws, 8);
    ws += __shfl_xor(ws, 16); ws += __shfl_xor(ws, 32);
    if (lane == 0) s_redB[wv] = ws;          // wave sum = 2 * true partial
    if (half == 0) s_xtld[f] = pe * xtv;     // unnormalized
    __syncthreads();                                   // b2

    // D: z[k] = (xtld . eK)*invS + h . eR + eb
    float4 sA = *(const float4*)&s_redB[0];
    float4 sB = *(const float4*)&s_redB[4];
    float Sr = ((sA.x+sA.y)+(sA.z+sA.w)) + ((sB.x+sB.y)+(sB.z+sB.w));
    float invS = rcpf_(0.5f*Sr);
    float pa = 0.f;
#pragma unroll
    for (int q4 = 0; q4 < 32; ++q4) {
      float4 xt = *(const float4*)&s_xtld[half*128 + q4*4];
      pa = fmaf(xt.x, eKr[q4*4+0], pa);
      pa = fmaf(xt.y, eKr[q4*4+1], pa);
      pa = fmaf(xt.z, eKr[q4*4+2], pa);
      pa = fmaf(xt.w, eKr[q4*4+3], pa);
    }
    float ph = 0.f;
#pragma unroll
    for (int j4 = 0; j4 < 8; ++j4) {
      float4 hv = *(const float4*)&s_h[half*32 + j4*4];
      float4 w4 = *(const float4*)&sWT[f*68 + half*32 + j4*4];
      ph = fmaf(hv.x, w4.x, ph); ph = fmaf(hv.y, w4.y, ph);
      ph = fmaf(hv.z, w4.z, ph); ph = fmaf(hv.w, w4.w, ph);
    }
    float v = fmaf(pa, invS, ph);
    float z = v + __shfl_xor(v, 1) + eb_k;
    int gate = f >> 6;                                  // wave-uniform
    float a = (gate == 2) ? tanh_e(z) : sigm(z);
    if (half == 0) s_ag[f] = a;
    __syncthreads();                                   // b3

    if (tid < 64) {
      float cn = fmaf(s_ag[64+tid], s_c[tid], s_ag[tid]*s_ag[128+tid]);
      float hn = s_ag[192+tid]*tanh_e(cn);
      s_c[tid] = cn; s_h[tid] = hn; s_xenc[t*65 + tid] = hn;
    }
    __syncthreads();                                   // b4
  }

  // ---------------- decoder prologue ----------------
  for (int i = tid; i < 4096; i += 512) sW[i]        = adW[8192 + i];  // Wd_x
  for (int i = tid; i < 4160; i += 512) sW[4096 + i] = fcW[i];         // fcW (65x64)
  if (tid < 64) { s_yprev[tid] = inb[tid*256 + 255]; s_h[tid] = 0.f; s_c[tid] = 0.f; }
  __syncthreads();

  // xe_proj[t'][u] -> pd = exp(2*xe), t' = u8, u = grp*8+q  (step-invariant)
  float pd[8];
  {
    float xe[8];
#pragma unroll
    for (int q = 0; q < 8; ++q) xe[q] = 0.f;
    for (int e = 0; e < 64; ++e) {
      float xv = s_xenc[u8*65 + e];
      float4 w0 = *(const float4*)&sW[e*64 + grp*8];
      float4 w1 = *(const float4*)&sW[e*64 + grp*8 + 4];
      xe[0]=fmaf(xv,w0.x,xe[0]); xe[1]=fmaf(xv,w0.y,xe[1]);
      xe[2]=fmaf(xv,w0.z,xe[2]); xe[3]=fmaf(xv,w0.w,xe[3]);
      xe[4]=fmaf(xv,w1.x,xe[4]); xe[5]=fmaf(xv,w1.y,xe[5]);
      xe[6]=fmaf(xv,w1.z,xe[6]); xe[7]=fmaf(xv,w1.w,xe[7]);
    }
#pragma unroll
    for (int q = 0; q < 8; ++q) pd[q] = __expf(2.0f*xe[q]);
  }

  // fold fc layer into LSTM input: M1 = fcW_ctx . dK (regs), m2 = fcW_y . dK,
  // mb = fcb . dK + db   -> y_tilde phase eliminated.
  float macc[32];
#pragma unroll
  for (int i = 0; i < 32; ++i) macc[i] = 0.f;
  float m2k = 0.f, mbk = dbg[f];
  for (int j4 = 0; j4 < 16; ++j4) {
    float d0 = dKg[(j4*4+0)*256 + f];
    float d1 = dKg[(j4*4+1)*256 + f];
    float d2 = dKg[(j4*4+2)*256 + f];
    float d3 = dKg[(j4*4+3)*256 + f];
#pragma unroll
    for (int ii = 0; ii < 32; ++ii) {
      float4 w = *(const float4*)&sW[4096 + (half*32+ii)*64 + j4*4];
      macc[ii] = fmaf(w.x, d0, macc[ii]);
      macc[ii] = fmaf(w.y, d1, macc[ii]);
      macc[ii] = fmaf(w.z, d2, macc[ii]);
      macc[ii] = fmaf(w.w, d3, macc[ii]);
    }
    float4 wr = *(const float4*)&sW[4096 + 4096 + j4*4];   // fcW row 64
    m2k = fmaf(wr.x, d0, m2k); m2k = fmaf(wr.y, d1, m2k);
    m2k = fmaf(wr.z, d2, m2k); m2k = fmaf(wr.w, d3, m2k);
    mbk = fmaf(fcb[j4*4+0], d0, mbk); mbk = fmaf(fcb[j4*4+1], d1, mbk);
    mbk = fmaf(fcb[j4*4+2], d2, mbk); mbk = fmaf(fcb[j4*4+3], d3, mbk);
  }

  float dRr[32];
#pragma unroll
  for (int jj = 0; jj < 32; ++jj) dRr[jj] = dRg[(half*32+jj)*256 + f];
  float wdd[8], wdc[8], advr[8];
#pragma unroll
  for (int jj = 0; jj < 8; ++jj) {
    wdd[jj]  = adW[(grp*8+jj)*64 + u8];
    wdc[jj]  = adW[(64+grp*8+jj)*64 + u8];
    advr[jj] = adv[grp*8+jj];
  }
  const float adb_u = adb[u8];
  __syncthreads();

  // ---------------- decoder loop ----------------
  for (int t = 0; t < 64; ++t) {
    // A: dc_u -> E_u
    float4 h0 = *(const float4*)&s_h[grp*8];
    float4 h1 = *(const float4*)&s_h[grp*8+4];
    float4 c0 = *(const float4*)&s_c[grp*8];
    float4 c1 = *(const float4*)&s_c[grp*8+4];
    float p = 0.f;
    p = fmaf(h0.x, wdd[0], p);  p = fmaf(h0.y, wdd[1], p);
    p = fmaf(h0.z, wdd[2], p);  p = fmaf(h0.w, wdd[3], p);
    p = fmaf(h1.x, wdd[4], p);  p = fmaf(h1.y, wdd[5], p);
    p = fmaf(h1.z, wdd[6], p);  p = fmaf(h1.w, wdd[7], p);
    p = fmaf(c0.x, wdc[0], p);  p = fmaf(c0.y, wdc[1], p);
    p = fmaf(c0.z, wdc[2], p);  p = fmaf(c0.w, wdc[3], p);
    p = fmaf(c1.x, wdc[4], p);  p = fmaf(c1.y, wdc[5], p);
    p = fmaf(c1.z, wdc[6], p);  p = fmaf(c1.w, wdc[7], p);
    p += __shfl_xor(p, 1); p += __shfl_xor(p, 2); p += __shfl_xor(p, 4);
    float E = __expf(2.0f*(p + adb_u));
    if (grp == 0) s_hs[u8] = E;
    __syncthreads();                                   // b1

    // C: scores over t'=u8, u-slice grp*8+[0,8)
    float4 E0 = *(const float4*)&s_hs[grp*8];
    float4 E1 = *(const float4*)&s_hs[grp*8+4];
    float sc = 0.f;
    {
      float q0=E0.x*pd[0], q1=E0.y*pd[1], q2=E0.z*pd[2], q3=E0.w*pd[3];
      float q4=E1.x*pd[4], q5=E1.y*pd[5], q6=E1.z*pd[6], q7=E1.w*pd[7];
      sc = fmaf((q0-1.f)*rcpf_(q0+1.f), advr[0], sc);
      sc = fmaf((q1-1.f)*rcpf_(q1+1.f), advr[1], sc);
      sc = fmaf((q2-1.f)*rcpf_(q2+1.f), advr[2], sc);
      sc = fmaf((q3-1.f)*rcpf_(q3+1.f), advr[3], sc);
      sc = fmaf((q4-1.f)*rcpf_(q4+1.f), advr[4], sc);
      sc = fmaf((q5-1.f)*rcpf_(q5+1.f), advr[5], sc);
      sc = fmaf((q6-1.f)*rcpf_(q6+1.f), advr[6], sc);
      sc = fmaf((q7-1.f)*rcpf_(q7+1.f), advr[7], sc);
    }
    sc += __shfl_xor(sc, 1); sc += __shfl_xor(sc, 2); sc += __shfl_xor(sc, 4);
    float pe = __expf(sc);
    float ws = pe;
    ws += __shfl_xor(ws, 1);  ws += __shfl_xor(ws, 2);
    ws += __shfl_xor(ws, 4);  ws += __shfl_xor(ws, 8);
    ws += __shfl_xor(ws, 16); ws += __shfl_xor(ws, 32);
    if (lane == 0) s_redB[wv] = ws;          // wave sum = 8 * true partial
    if (grp == 0) s_pe[u8] = pe;
    __syncthreads();                                   // b2

    // CTX: context[e=u8] = invS * sum_t pe_t * xenc[t][e]
    float4 sA = *(const float4*)&s_redB[0];
    float4 sB = *(const float4*)&s_redB[4];
    float Sr = ((sA.x+sA.y)+(sA.z+sA.w)) + ((sB.x+sB.y)+(sB.z+sB.w));
    float invS = rcpf_(0.125f*Sr);
    float pc = 0.f;
#pragma unroll
    for (int q = 0; q < 8; ++q)
      pc = fmaf(s_pe[grp*8+q], s_xenc[(grp*8+q)*65 + u8], pc);
    pc += __shfl_xor(pc, 1); pc += __shfl_xor(pc, 2); pc += __shfl_xor(pc, 4);
    float ce = pc * invS;
    if (grp == 0) s_ctx[u8] = ce;
    __syncthreads();                                   // b3

    // I: z[k] = ctx . M1 + y*m2 + mb + d . dR
    float pa = 0.f;
#pragma unroll
    for (int i4 = 0; i4 < 8; ++i4) {
      float4 cv = *(const float4*)&s_ctx[half*32 + i4*4];
      pa = fmaf(cv.x, macc[i4*4+0], pa);
      pa = fmaf(cv.y, macc[i4*4+1], pa);
      pa = fmaf(cv.z, macc[i4*4+2], pa);
      pa = fmaf(cv.w, macc[i4*4+3], pa);
    }
#pragma unroll
    for (int j4 = 0; j4 < 8; ++j4) {
      float4 hv = *(const float4*)&s_h[half*32 + j4*4];
      pa = fmaf(hv.x, dRr[j4*4+0], pa);
      pa = fmaf(hv.y, dRr[j4*4+1], pa);
      pa = fmaf(hv.z, dRr[j4*4+2], pa);
      pa = fmaf(hv.w, dRr[j4*4+3], pa);
    }
    float y_t = s_yprev[t];
    if (half == 0) pa = fmaf(y_t, m2k, pa + mbk);
    float z = pa + __shfl_xor(pa, 1);
    int gate = f >> 6;
    float a = (gate == 2) ? tanh_e(z) : sigm(z);
    if (half == 0) s_ag[f] = a;
    __syncthreads();                                   // b4

    if (tid < 64) {
      float cn = fmaf(s_ag[64+tid], s_c[tid], s_ag[tid]*s_ag[128+tid]);
      s_c[tid] = cn;
      s_h[tid] = s_ag[192+tid]*tanh_e(cn);
    }
    __syncthreads();                                   // b5
  }

  // ---------------- epilogue: out = [d_n, ctx] @ fcfW + fcfb ----------------
  {
    const float* src = half ? s_ctx : s_h;   // half0: rows 0..63, half1: 64..127
    float pa = 0.f;
#pragma unroll
    for (int j4 = 0; j4 < 16; ++j4) {
      float4 v = *(const float4*)&src[j4*4];
      pa = fmaf(v.x, fcfW[(half*64 + j4*4+0)*256 + f], pa);
      pa = fmaf(v.y, fcfW[(half*64 + j4*4+1)*256 + f], pa);
      pa = fmaf(v.z, fcfW[(half*64 + j4*4+2)*256 + f], pa);
      pa = fmaf(v.w, fcfW[(half*64 + j4*4+3)*256 + f], pa);
    }
    float r = pa + __shfl_xor(pa, 1);
    if (half == 0) out[b*256 + f] = r + fcfb[f];
  }
}

extern "C" void kernel_launch(void* const* d_in, const int* in_sizes, int n_in,
                              void* d_out, int out_size, void* d_ws, size_t ws_size,
                              hipStream_t stream) {
  const float* gin  = (const float*)d_in[0];
  const float* eK   = (const float*)d_in[1];
  const float* eR   = (const float*)d_in[2];
  const float* eb   = (const float*)d_in[3];
  const float* dK   = (const float*)d_in[4];
  const float* dR   = (const float*)d_in[5];
  const float* db   = (const float*)d_in[6];
  const float* aeW  = (const float*)d_in[7];
  const float* aeb  = (const float*)d_in[8];
  const float* aev  = (const float*)d_in[9];
  // d_in[10] attn_e_vb, d_in[14] attn_d_vb: constant shifts, cancel in softmax
  const float* adW  = (const float*)d_in[11];
  const float* adb  = (const float*)d_in[12];
  const float* adv  = (const float*)d_in[13];
  const float* fcW  = (const float*)d_in[15];
  const float* fcb  = (const float*)d_in[16];
  const float* fcfW = (const float*)d_in[17];
  const float* fcfb = (const float*)d_in[18];
  float* out = (float*)d_out;

  const int B = in_sizes[0] / (64*256);
  hipLaunchKernelGGL(darnn_fused, dim3(B), dim3(512), 0, stream,
                     gin, eK, eR, eb, dK, dR, db, aeW, aeb, aev,
                     adW, adb, adv, fcW, fcb, fcfW, fcfb, out);
}